// Round 11
// baseline (734.867 us; speedup 1.0000x reference)
//
#include <hip/hip_runtime.h>
#include <hip/hip_bf16.h>
#include <math.h>

// Problem constants
#define BB 2
#define NN 4096
#define PP (BB*NN)      // 8192 points total
#define KK 20
#define LEAK 0.2f
#define EPSB 1e-5f

typedef short sv8 __attribute__((ext_vector_type(8)));   // 8 bf16 (4 VGPRs)
typedef float f4  __attribute__((ext_vector_type(4)));   // 4 fp32 acc

__device__ inline unsigned short f2bf(float f) {         // RNE fp32->bf16
    unsigned u = __float_as_uint(f);
    unsigned r = (u + 0x7FFFu + ((u >> 16) & 1u)) >> 16;
    return (unsigned short)r;
}
__device__ inline float bf2f(unsigned short h) {
    return __uint_as_float((unsigned)h << 16);
}
__device__ inline void gload16(const void* g, void* l) {
    __builtin_amdgcn_global_load_lds(
        (const __attribute__((address_space(1))) unsigned int*)g,
        (__attribute__((address_space(3))) unsigned int*)l, 16, 0, 0);
}

// ---------------------------------------------------------------------------
// kNN (verified R5-R10) + fused: layer-1 projection (f32 u/v), weight
// conversion for layers 2..5 (blocks 0..1375), acc zeroing (blocks 4096..4107).
__global__ __launch_bounds__(256) void knn_kernel(const float* __restrict__ pts,
                                                  int* __restrict__ idx,
                                                  const float* __restrict__ w1,
                                                  float* __restrict__ u1,
                                                  float* __restrict__ v1,
                                                  const float* __restrict__ w2,
                                                  const float* __restrict__ w3,
                                                  const float* __restrict__ w4,
                                                  const float* __restrict__ w5,
                                                  unsigned short* __restrict__ wh_all,
                                                  unsigned short* __restrict__ wl_all,
                                                  float* __restrict__ acc_all) {
    __shared__ unsigned int hist[256];
    __shared__ unsigned int scanres[3];
    __shared__ unsigned int cnt2[2];
    __shared__ unsigned long long blist[512];

    int r = blockIdx.x;            // b*N + n
    int tid = threadIdx.x;

    // ---- fused side work (independent of knn; consumed by later dispatches)
    if (r < 1376) {
        int i = r * 256 + tid;
        if (i < 352256) {
            const float* w; int O, C, mode, base;
            if (i < 8192)       { w = w2; O = 64;  C = 64;  mode = 0; base = 0; }
            else if (i < 24576) { w = w3; O = 128; C = 64;  mode = 0; base = 8192; }
            else if (i < 90112) { w = w4; O = 256; C = 128; mode = 0; base = 24576; }
            else                { w = w5; O = 512; C = 512; mode = 1; base = 90112; }
            int j = i - base;
            int row = j / C, c = j - row * C;
            float v;
            if (mode == 0) {
                if (row < O) v = w[(size_t)row * 2 * C + c];
                else {
                    const float* wr = w + (size_t)(row - O) * 2 * C;
                    v = wr[C + c] - wr[c];
                }
            } else {
                v = w[(size_t)row * C + c];
            }
            unsigned short h = f2bf(v);
            wh_all[i] = h;
            wl_all[i] = f2bf(v - bf2f(h));
        }
    } else if (r >= 4096 && r < 4108) {
        acc_all[(r - 4096) * 256 + tid] = 0.f;   // 3072 floats total
    }

    int b = r >> 12, n = r & (NN - 1);
    const float* X0 = pts + (size_t)b * 2 * NN;
    const float* X1 = X0 + NN;
    float x0n = X0[n], x1n = X1[n];
    float xxn = __fadd_rn(__fmul_rn(x0n, x0n), __fmul_rn(x1n, x1n));
    float negxxn = __fsub_rn(0.f, xxn);

    // fused layer-1 projection for this point (64 channels, f32)
    if (tid < 64) {
        float4 wr = *(const float4*)&w1[(size_t)tid * 4];
        u1[(size_t)r * 64 + tid] = fmaf(wr.x, x0n, wr.y * x1n);
        v1[(size_t)r * 64 + tid] = fmaf(wr.z - wr.x, x0n, (wr.w - wr.y) * x1n);
    }

    float pdv[16];
    #pragma unroll
    for (int q = 0; q < 16; ++q) {
        int m = q * 256 + tid;
        float x0m = X0[m], x1m = X1[m];
        float xxm = __fadd_rn(__fmul_rn(x0m, x0m), __fmul_rn(x1m, x1m));
        float dot = __builtin_fmaf(x1n, x1m, __fmul_rn(x0n, x0m));
        float inner = __fmul_rn(-2.f, dot);
        float t1 = __fsub_rn(negxxn, inner);
        pdv[q] = __fsub_rn(t1, xxm);
    }

    int bins[16];
    int shift = 24;
    for (int attempt = 0; attempt < 3; ++attempt) {
        hist[tid] = 0;
        __syncthreads();
        float scale = (float)(1u << shift);
        #pragma unroll
        for (int q = 0; q < 16; ++q) {
            float s = fmaxf(-pdv[q], 0.f);
            unsigned int ki = (unsigned int)fminf(s * scale, 4.294e9f);
            unsigned int bin = ki >> 16;
            if (bin > 255u) bin = 255u;
            bins[q] = (int)bin;
            if (bin < 255u) atomicAdd(&hist[bin], 1u);
        }
        __syncthreads();
        if (tid < 64) {
            uint4 hv = *(const uint4*)&hist[tid * 4];
            unsigned int p0 = hv.x, p1 = p0 + hv.y, p2 = p1 + hv.z, p3 = p2 + hv.w;
            unsigned int lanesum = p3, inc = p3;
            #pragma unroll
            for (int s2 = 1; s2 < 64; s2 <<= 1) {
                unsigned int o = __shfl_up(inc, s2, 64);
                if (tid >= s2) inc += o;
            }
            unsigned int excl = inc - lanesum;
            bool flag = (inc >= KK);
            unsigned long long bal = __ballot(flag);
            int firstlane = (bal == 0ULL) ? -1 : (__ffsll((long long)bal) - 1);
            if (tid == 0) scanres[0] = (bal != 0ULL) ? 1u : 0u;
            if (tid == firstlane) {
                unsigned int c0 = excl + p0, c1 = excl + p1, c2 = excl + p2;
                int t = (c0 >= KK) ? 0 : (c1 >= KK) ? 1 : (c2 >= KK) ? 2 : 3;
                unsigned int cumb = (t == 0) ? excl : (t == 1) ? c0 : (t == 2) ? c1 : c2;
                scanres[1] = (unsigned)(tid * 4 + t);
                scanres[2] = cumb;
            }
        }
        __syncthreads();
        if (scanres[0]) break;
        shift -= 6;
        __syncthreads();
    }

    int bstar = (int)scanres[1];
    unsigned int cumb = scanres[2];
    if (tid == 0) { cnt2[0] = 0; cnt2[1] = 0; }
    __syncthreads();

    #pragma unroll
    for (int q = 0; q < 16; ++q) {
        int bin = bins[q];
        int m = q * 256 + tid;
        if (bin < bstar) {
            unsigned int slot = atomicAdd(&cnt2[0], 1u);
            idx[(size_t)r * KK + slot] = m;
        } else if (bin == bstar) {
            unsigned int pos = atomicAdd(&cnt2[1], 1u);
            if (pos < 512u) {
                unsigned int ub = __float_as_uint(pdv[q]);
                unsigned int fk = (ub & 0x80000000u) ? ~ub : (ub | 0x80000000u);
                blist[pos] = ((unsigned long long)(~fk) << 32) | (unsigned int)m;
            }
        }
    }
    __syncthreads();

    int need = KK - (int)cumb;
    int L = (int)min(cnt2[1], 512u);
    if (tid < 64) {
        unsigned long long e[8];
        #pragma unroll
        for (int i = 0; i < 8; ++i) {
            int p = tid + 64 * i;
            e[i] = (p < L) ? blist[p] : ~0ULL;
        }
        unsigned long long lmin = e[0];
        #pragma unroll
        for (int i = 1; i < 8; ++i) lmin = (e[i] < lmin) ? e[i] : lmin;
        for (int p = 0; p < need; ++p) {
            unsigned long long gm = lmin;
            #pragma unroll
            for (int s2 = 32; s2 > 0; s2 >>= 1) {
                unsigned long long o = __shfl_xor(gm, s2, 64);
                if (o < gm) gm = o;
            }
            if (lmin == gm) {
                #pragma unroll
                for (int i = 0; i < 8; ++i) if (e[i] == gm) e[i] = ~0ULL;
                lmin = e[0];
                #pragma unroll
                for (int i = 1; i < 8; ++i) lmin = (e[i] < lmin) ? e[i] : lmin;
                idx[(size_t)r * KK + cumb + p] = (int)(gm & 0xFFFFFFFFu);
            }
        }
    }
}

// ---------------------------------------------------------------------------
// Split-bf16 MFMA GEMM, 64x64 tile (verified R7-R10), f32 outputs.
__global__ __launch_bounds__(256) void mfma_gemm64(const unsigned short* __restrict__ Xh,
                                                   const unsigned short* __restrict__ Xl,
                                                   int ldx, int K,
                                                   const unsigned short* __restrict__ Bh,
                                                   const unsigned short* __restrict__ Bl,
                                                   int O,
                                                   float* __restrict__ outU,
                                                   float* __restrict__ outV) {
    __shared__ unsigned short Ah[256 * 8], Al[256 * 8], Bhs[256 * 8], Bls[256 * 8];
    int row0 = blockIdx.x * 64, col0 = blockIdx.y * 64;
    int tid = threadIdx.x;
    int wid = tid >> 6, lane = tid & 63;
    int wm = wid & 1, wn = wid >> 1;
    int l15 = lane & 15, l4 = lane >> 4;
    int m = tid & 63, kb = tid >> 6;

    f4 acc[2][2];
    #pragma unroll
    for (int i = 0; i < 2; ++i)
        #pragma unroll
        for (int j = 0; j < 2; ++j) { acc[i][j][0]=0.f; acc[i][j][1]=0.f; acc[i][j][2]=0.f; acc[i][j][3]=0.f; }

    for (int k0 = 0; k0 < K; k0 += 32) {
        size_t ga = (size_t)(row0 + m) * ldx + k0 + kb * 8;
        size_t gb = (size_t)(col0 + m) * K + k0 + kb * 8;
        gload16(Xh + ga, &Ah[(size_t)(wid * 64) * 8]);
        gload16(Xl + ga, &Al[(size_t)(wid * 64) * 8]);
        gload16(Bh + gb, &Bhs[(size_t)(wid * 64) * 8]);
        gload16(Bl + gb, &Bls[(size_t)(wid * 64) * 8]);
        __syncthreads();

        sv8 bhf[2], blf[2];
        #pragma unroll
        for (int fn = 0; fn < 2; ++fn) {
            int nn2 = wn * 32 + fn * 16 + l15;
            bhf[fn] = *(const sv8*)&Bhs[(size_t)(l4 * 64 + nn2) * 8];
            blf[fn] = *(const sv8*)&Bls[(size_t)(l4 * 64 + nn2) * 8];
        }
        #pragma unroll
        for (int fm = 0; fm < 2; ++fm) {
            int mm = wm * 32 + fm * 16 + l15;
            sv8 ah = *(const sv8*)&Ah[(size_t)(l4 * 64 + mm) * 8];
            sv8 al = *(const sv8*)&Al[(size_t)(l4 * 64 + mm) * 8];
            #pragma unroll
            for (int fn = 0; fn < 2; ++fn) {
                acc[fm][fn] = __builtin_amdgcn_mfma_f32_16x16x32_bf16(ah, bhf[fn], acc[fm][fn], 0, 0, 0);
                acc[fm][fn] = __builtin_amdgcn_mfma_f32_16x16x32_bf16(ah, blf[fn], acc[fm][fn], 0, 0, 0);
                acc[fm][fn] = __builtin_amdgcn_mfma_f32_16x16x32_bf16(al, bhf[fn], acc[fm][fn], 0, 0, 0);
            }
        }
        __syncthreads();
    }

    #pragma unroll
    for (int fm = 0; fm < 2; ++fm) {
        int rbase = row0 + wm * 32 + fm * 16 + l4 * 4;
        #pragma unroll
        for (int fn = 0; fn < 2; ++fn) {
            int jg = col0 + wn * 32 + fn * 16 + l15;
            #pragma unroll
            for (int e = 0; e < 4; ++e) {
                float vv = acc[fm][fn][e];
                int p = rbase + e;
                if (jg < O) outU[(size_t)p * O + jg] = vv;
                else        outV[(size_t)p * O + (jg - O)] = vv;
            }
        }
    }
}

// ---------------------------------------------------------------------------
// Single-plane bf16 MFMA GEMM, 128x128 tile (final conv) + fused BN partial
// stats accumulated via device-scope atomics into facc[ch*2 {s1,s2}].
__global__ __launch_bounds__(256) void mfma_gemm128s(const unsigned short* __restrict__ Xh,
                                                     int ldx, int K,
                                                     const unsigned short* __restrict__ Bh,
                                                     int O,
                                                     float* __restrict__ outU,
                                                     float* __restrict__ facc) {
    __shared__ unsigned short Ah[512 * 8], Bhs[512 * 8];
    __shared__ float sred1[2][128], sred2[2][128];
    int row0 = blockIdx.x * 128, col0 = blockIdx.y * 128;
    int tid = threadIdx.x;
    int wid = tid >> 6, lane = tid & 63;
    int wm = wid & 1, wn = wid >> 1;
    int l15 = lane & 15, l4 = lane >> 4;

    f4 acc[4][4];
    #pragma unroll
    for (int i = 0; i < 4; ++i)
        #pragma unroll
        for (int j = 0; j < 4; ++j) { acc[i][j][0]=0.f; acc[i][j][1]=0.f; acc[i][j][2]=0.f; acc[i][j][3]=0.f; }

    for (int k0 = 0; k0 < K; k0 += 32) {
        #pragma unroll
        for (int j = 0; j < 2; ++j) {
            int c = tid + 256 * j;
            int m = c & 127, kb = c >> 7;
            size_t ga = (size_t)(row0 + m) * ldx + k0 + kb * 8;
            size_t gb = (size_t)(col0 + m) * K + k0 + kb * 8;
            gload16(Xh + ga, &Ah[(size_t)(wid * 64 + 256 * j) * 8]);
            gload16(Bh + gb, &Bhs[(size_t)(wid * 64 + 256 * j) * 8]);
        }
        __syncthreads();

        sv8 bhf[4];
        #pragma unroll
        for (int fn = 0; fn < 4; ++fn) {
            int nn2 = wn * 64 + fn * 16 + l15;
            bhf[fn] = *(const sv8*)&Bhs[(size_t)(l4 * 128 + nn2) * 8];
        }
        #pragma unroll
        for (int fm = 0; fm < 4; ++fm) {
            int mm = wm * 64 + fm * 16 + l15;
            sv8 ah = *(const sv8*)&Ah[(size_t)(l4 * 128 + mm) * 8];
            #pragma unroll
            for (int fn = 0; fn < 4; ++fn)
                acc[fm][fn] = __builtin_amdgcn_mfma_f32_16x16x32_bf16(ah, bhf[fn], acc[fm][fn], 0, 0, 0);
        }
        __syncthreads();
    }

    #pragma unroll
    for (int fm = 0; fm < 4; ++fm) {
        int rbase = row0 + wm * 64 + fm * 16 + l4 * 4;
        #pragma unroll
        for (int fn = 0; fn < 4; ++fn) {
            int jg = col0 + wn * 64 + fn * 16 + l15;
            #pragma unroll
            for (int e = 0; e < 4; ++e)
                outU[(size_t)(rbase + e) * O + jg] = acc[fm][fn][e];
        }
    }

    #pragma unroll
    for (int fn = 0; fn < 4; ++fn) {
        float a1 = 0.f, a2 = 0.f;
        #pragma unroll
        for (int fm = 0; fm < 4; ++fm)
            #pragma unroll
            for (int e = 0; e < 4; ++e) { float t = acc[fm][fn][e]; a1 += t; a2 = fmaf(t, t, a2); }
        a1 += __shfl_xor(a1, 16, 64); a2 += __shfl_xor(a2, 16, 64);
        a1 += __shfl_xor(a1, 32, 64); a2 += __shfl_xor(a2, 32, 64);
        if (lane < 16) {
            int cb = wn * 64 + fn * 16 + lane;
            sred1[wm][cb] = a1;
            sred2[wm][cb] = a2;
        }
    }
    __syncthreads();
    if (tid < 128) {
        float s1 = sred1[0][tid] + sred1[1][tid];
        float s2 = sred2[0][tid] + sred2[1][tid];
        atomicAdd(&facc[(size_t)(col0 + tid) * 2],     s1);
        atomicAdd(&facc[(size_t)(col0 + tid) * 2 + 1], s2);
    }
}

// ---------------------------------------------------------------------------
// edge_stats v4: f32 float2 channel pairs, full prefetch, LDS block reduce,
// then device-scope atomicAdd into accL[ch*2 {s1,s2}] (replaces partial+reduce).
__global__ __launch_bounds__(256) void edge_stats(const float* __restrict__ u,
                                                  const float* __restrict__ v,
                                                  const int* __restrict__ idx,
                                                  int O, int PPL,
                                                  float* __restrict__ mx, float* __restrict__ mn,
                                                  float* __restrict__ accL) {
    __shared__ float red[4 * 256];
    int tid = threadIdx.x;
    int CH2 = O >> 1;
    int PS = 256 / CH2;
    int co = tid % CH2;
    int ps = tid / CH2;
    float s1a = 0.f, s1b = 0.f, s2a = 0.f, s2b = 0.f;
    for (int pi = 0; pi < PPL; ++pi) {
        int r = (blockIdx.x * PS + ps) * PPL + pi;
        int b = r >> 12;
        const float* ub = u + (size_t)b * NN * O + 2 * co;
        float2 vv = *(const float2*)&v[(size_t)r * O + 2 * co];
        const int* ip = idx + (size_t)r * KK;
        int mreg[KK];
        #pragma unroll
        for (int k = 0; k < KK; ++k) mreg[k] = ip[k];
        float2 uv[KK];
        #pragma unroll
        for (int k = 0; k < KK; ++k) uv[k] = *(const float2*)&ub[(size_t)mreg[k] * O];
        float bxa = -INFINITY, bxb = -INFINITY, bna = INFINITY, bnb = INFINITY;
        #pragma unroll
        for (int k = 0; k < KK; ++k) {
            float y0 = uv[k].x + vv.x, y1 = uv[k].y + vv.y;
            s1a += y0; s2a = fmaf(y0, y0, s2a);
            s1b += y1; s2b = fmaf(y1, y1, s2b);
            bxa = fmaxf(bxa, y0); bna = fminf(bna, y0);
            bxb = fmaxf(bxb, y1); bnb = fminf(bnb, y1);
        }
        *(float2*)&mx[(size_t)r * O + 2 * co] = make_float2(bxa, bxb);
        *(float2*)&mn[(size_t)r * O + 2 * co] = make_float2(bna, bnb);
    }
    red[0 * 256 + tid] = s1a;
    red[1 * 256 + tid] = s1b;
    red[2 * 256 + tid] = s2a;
    red[3 * 256 + tid] = s2b;
    __syncthreads();
    for (int s = PS >> 1; s > 0; s >>= 1) {
        if (ps < s) {
            int oth = tid + s * CH2;
            red[0 * 256 + tid] += red[0 * 256 + oth];
            red[1 * 256 + tid] += red[1 * 256 + oth];
            red[2 * 256 + tid] += red[2 * 256 + oth];
            red[3 * 256 + tid] += red[3 * 256 + oth];
        }
        __syncthreads();
    }
    if (ps == 0) {
        atomicAdd(&accL[4 * co + 0], red[0 * 256 + tid]);   // s1 ch 2co
        atomicAdd(&accL[4 * co + 1], red[2 * 256 + tid]);   // s2 ch 2co
        atomicAdd(&accL[4 * co + 2], red[1 * 256 + tid]);   // s1 ch 2co+1
        atomicAdd(&accL[4 * co + 3], red[3 * 256 + tid]);   // s2 ch 2co+1
    }
}

// select max/min by scale sign, affine + LeakyReLU; st computed inline from
// accL sums (g, bsh); 2 channels/thread.
__global__ void apply_edge(const float* __restrict__ mx, const float* __restrict__ mn,
                           const float* __restrict__ accL,
                           const float* __restrict__ g, const float* __restrict__ bsh,
                           int O, int choff, float cnt,
                           unsigned short* __restrict__ xh, unsigned short* __restrict__ xl,
                           int writelo) {
    int e2 = blockIdx.x * 256 + threadIdx.x;
    int half = O >> 1;
    if (e2 >= PP * half) return;
    int r = e2 / half, co = e2 - r * half;
    int o = 2 * co;
    float4 a = *(const float4*)&accL[4 * co];        // s1a,s2a,s1b,s2b
    float mu0 = a.x / cnt, mu1 = a.z / cnt;
    float var0 = a.y / cnt - mu0 * mu0;
    float var1 = a.w / cnt - mu1 * mu1;
    float x0 = var0 + EPSB, x1 = var1 + EPSB;
    float r0 = rsqrtf(x0); r0 = r0 * (1.5f - 0.5f * x0 * r0 * r0);
    float r1 = rsqrtf(x1); r1 = r1 * (1.5f - 0.5f * x1 * r1 * r1);
    float2 gg = *(const float2*)&g[o];
    float2 bb = *(const float2*)&bsh[o];
    float sc0 = gg.x * r0, sc1 = gg.y * r1;
    float tt0 = bb.x - mu0 * sc0, tt1 = bb.y - mu1 * sc1;
    float2 vx = *(const float2*)&mx[(size_t)r * O + o];
    float2 vn = *(const float2*)&mn[(size_t)r * O + o];
    float b0 = (sc0 >= 0.f) ? vx.x : vn.x;
    float b1 = (sc1 >= 0.f) ? vx.y : vn.y;
    float y0 = fmaf(sc0, b0, tt0); y0 = (y0 >= 0.f) ? y0 : LEAK * y0;
    float y1 = fmaf(sc1, b1, tt1); y1 = (y1 >= 0.f) ? y1 : LEAK * y1;
    unsigned short h0 = f2bf(y0), h1 = f2bf(y1);
    size_t d = (size_t)r * 512 + choff + o;
    ((unsigned int*)xh)[d >> 1] = (unsigned int)h0 | ((unsigned int)h1 << 16);
    if (writelo) {
        unsigned short l0 = f2bf(y0 - bf2f(h0)), l1 = f2bf(y1 - bf2f(h1));
        ((unsigned int*)xl)[d >> 1] = (unsigned int)l0 | ((unsigned int)l1 << 16);
    }
}

// ---------------------------------------------------------------------------
// affine+lrelu + transpose (B,N,512) -> (B,512,N); st inline from facc.
__global__ __launch_bounds__(256) void final_apply(const float* __restrict__ y5,
                                                   const float* __restrict__ facc,
                                                   const float* __restrict__ g,
                                                   const float* __restrict__ bsh,
                                                   float cnt,
                                                   float* __restrict__ out) {
    __shared__ float tile[32][33];
    int n0 = blockIdx.x * 32, o0 = blockIdx.y * 32, b = blockIdx.z;
    int tx = threadIdx.x, ty = threadIdx.y;
    for (int i = 0; i < 4; ++i) {
        int nl = ty + i * 8;
        tile[nl][tx] = y5[((size_t)(b * NN + n0 + nl)) * 512 + o0 + tx];
    }
    __syncthreads();
    for (int i = 0; i < 4; ++i) {
        int ol = ty + i * 8;
        int o = o0 + ol;
        float2 a = *(const float2*)&facc[(size_t)o * 2];   // s1, s2
        float mu = a.x / cnt;
        float var = a.y / cnt - mu * mu;
        float x = var + EPSB;
        float rr = rsqrtf(x);
        rr = rr * (1.5f - 0.5f * x * rr * rr);
        float sc = g[o] * rr;
        float tt = bsh[o] - mu * sc;
        float yv = fmaf(sc, tile[tx][ol], tt);
        yv = (yv >= 0.f) ? yv : LEAK * yv;
        out[((size_t)b * 512 + o) * NN + n0 + tx] = yv;
    }
}

// ---------------------------------------------------------------------------
extern "C" void kernel_launch(void* const* d_in, const int* in_sizes, int n_in,
                              void* d_out, int out_size, void* d_ws, size_t ws_size,
                              hipStream_t stream) {
    const float* pts = (const float*)d_in[0];
    const float* w[5]; const float* g[5]; const float* bsh[5];
    for (int i = 0; i < 5; ++i) {
        w[i]   = (const float*)d_in[1 + 3 * i];
        g[i]   = (const float*)d_in[2 + 3 * i];
        bsh[i] = (const float*)d_in[3 + 3 * i];
    }
    float* out = (float*)d_out;

    // workspace layout
    unsigned short* xh = (unsigned short*)d_ws;              // PP*512 bf16 hi
    unsigned short* xl = xh + (size_t)PP * 512;              // PP*512 bf16 lo
    float* u    = (float*)(xl + (size_t)PP * 512);           // PP*256 f32
    float* v    = u    + (size_t)PP * 256;                   // PP*256 f32
    float* mxb  = v    + (size_t)PP * 256;                   // PP*256 f32
    float* mnb  = mxb  + (size_t)PP * 256;                   // PP*256 f32
    float* y5   = mxb;                                       // overlay (PP*512, mx/mn dead by then)
    int*   idxb = (int*)(mnb + (size_t)PP * 256);            // PP*20
    float* acc_all = (float*)(idxb + (size_t)PP * KK);       // 3072 floats (zeroed by knn)
    // acc offsets: l1@0, l2@512, l3@1024, l4@1536, facc@2048
    unsigned short* wh_all = (unsigned short*)(acc_all + 3072); // 352256 persistent
    unsigned short* wl_all = wh_all + 352256;                   // 352256

    knn_kernel<<<PP, 256, 0, stream>>>(pts, idxb, w[0], u, v,
                                       w[1], w[2], w[3], w[4], wh_all, wl_all, acc_all);

    const int Cs[4]     = {2, 64, 64, 128};
    const int Os[4]     = {64, 64, 128, 256};
    const int choffs[4] = {0, 64, 128, 256};
    const int inoffs[4] = {0, 0, 64, 128};
    const int woffs[4]  = {0, 0, 8192, 24576};
    const int aoffs[4]  = {0, 512, 1024, 1536};
    float cntE = (float)((size_t)PP * KK);

    for (int li = 0; li < 4; ++li) {
        int C = Cs[li], O = Os[li];
        if (li > 0) {
            dim3 gg(PP / 64, (2 * O) / 64);
            mfma_gemm64<<<gg, 256, 0, stream>>>(xh + inoffs[li], xl + inoffs[li], 512, C,
                                                wh_all + woffs[li], wl_all + woffs[li], O, u, v);
        }
        int PS  = 512 / O;
        int PPL = (O == 256) ? 2 : 1;
        int nblk = PP / (PS * PPL);
        edge_stats<<<nblk, 256, 0, stream>>>(u, v, idxb, O, PPL, mxb, mnb, acc_all + aoffs[li]);
        apply_edge<<<(PP * O / 2 + 255) / 256, 256, 0, stream>>>(
            mxb, mnb, acc_all + aoffs[li], g[li], bsh[li], O, choffs[li], cntE,
            xh, xl, (li == 3) ? 0 : 1);
    }

    // final conv1d 512->512 (single-plane bf16 MFMA, atomic BN stats)
    dim3 gf(PP / 128, 512 / 128);
    mfma_gemm128s<<<gf, 256, 0, stream>>>(xh, 512, 512, wh_all + 90112, 512, y5, acc_all + 2048);
    final_apply<<<dim3(NN / 32, 512 / 32, BB), dim3(32, 8), 0, stream>>>(
        y5, acc_all + 2048, g[4], bsh[4], (float)PP, out);
}

// Round 12
// 187.050 us; speedup vs baseline: 3.9287x; 3.9287x over previous
//
#include <hip/hip_runtime.h>
#include <hip/hip_bf16.h>
#include <math.h>

// Problem constants
#define BB 2
#define NN 4096
#define PP (BB*NN)      // 8192 points total
#define KK 20
#define LEAK 0.2f
#define EPSB 1e-5f

typedef short sv8 __attribute__((ext_vector_type(8)));   // 8 bf16 (4 VGPRs)
typedef float f4  __attribute__((ext_vector_type(4)));   // 4 fp32 acc

__device__ inline unsigned short f2bf(float f) {         // RNE fp32->bf16
    unsigned u = __float_as_uint(f);
    unsigned r = (u + 0x7FFFu + ((u >> 16) & 1u)) >> 16;
    return (unsigned short)r;
}
__device__ inline float bf2f(unsigned short h) {
    return __uint_as_float((unsigned)h << 16);
}
__device__ inline void gload16(const void* g, void* l) {
    __builtin_amdgcn_global_load_lds(
        (const __attribute__((address_space(1))) unsigned int*)g,
        (__attribute__((address_space(3))) unsigned int*)l, 16, 0, 0);
}

// ---------------------------------------------------------------------------
// kNN (verified R5-R10) + fused: layer-1 projection (f32 u/v), weight
// conversion for layers 2..5 (blocks 0..1375), facc zeroing (blocks 4096..4099).
__global__ __launch_bounds__(256) void knn_kernel(const float* __restrict__ pts,
                                                  int* __restrict__ idx,
                                                  const float* __restrict__ w1,
                                                  float* __restrict__ u1,
                                                  float* __restrict__ v1,
                                                  const float* __restrict__ w2,
                                                  const float* __restrict__ w3,
                                                  const float* __restrict__ w4,
                                                  const float* __restrict__ w5,
                                                  unsigned short* __restrict__ wh_all,
                                                  unsigned short* __restrict__ wl_all,
                                                  float* __restrict__ facc) {
    __shared__ unsigned int hist[256];
    __shared__ unsigned int scanres[3];
    __shared__ unsigned int cnt2[2];
    __shared__ unsigned long long blist[512];

    int r = blockIdx.x;            // b*N + n
    int tid = threadIdx.x;

    // ---- fused side work (independent of knn; consumed later, stream-serial)
    if (r < 1376) {
        int i = r * 256 + tid;
        if (i < 352256) {
            const float* w; int O, C, mode, base;
            if (i < 8192)       { w = w2; O = 64;  C = 64;  mode = 0; base = 0; }
            else if (i < 24576) { w = w3; O = 128; C = 64;  mode = 0; base = 8192; }
            else if (i < 90112) { w = w4; O = 256; C = 128; mode = 0; base = 24576; }
            else                { w = w5; O = 512; C = 512; mode = 1; base = 90112; }
            int j = i - base;
            int row = j / C, c = j - row * C;
            float v;
            if (mode == 0) {
                if (row < O) v = w[(size_t)row * 2 * C + c];
                else {
                    const float* wr = w + (size_t)(row - O) * 2 * C;
                    v = wr[C + c] - wr[c];
                }
            } else {
                v = w[(size_t)row * C + c];
            }
            unsigned short h = f2bf(v);
            wh_all[i] = h;
            wl_all[i] = f2bf(v - bf2f(h));
        }
    } else if (r >= 4096 && r < 4100) {
        facc[(r - 4096) * 256 + tid] = 0.f;   // 1024 floats total
    }

    int b = r >> 12, n = r & (NN - 1);
    const float* X0 = pts + (size_t)b * 2 * NN;
    const float* X1 = X0 + NN;
    float x0n = X0[n], x1n = X1[n];
    float xxn = __fadd_rn(__fmul_rn(x0n, x0n), __fmul_rn(x1n, x1n));
    float negxxn = __fsub_rn(0.f, xxn);

    // fused layer-1 projection for this point (64 channels, f32)
    if (tid < 64) {
        float4 wr = *(const float4*)&w1[(size_t)tid * 4];
        u1[(size_t)r * 64 + tid] = fmaf(wr.x, x0n, wr.y * x1n);
        v1[(size_t)r * 64 + tid] = fmaf(wr.z - wr.x, x0n, (wr.w - wr.y) * x1n);
    }

    float pdv[16];
    #pragma unroll
    for (int q = 0; q < 16; ++q) {
        int m = q * 256 + tid;
        float x0m = X0[m], x1m = X1[m];
        float xxm = __fadd_rn(__fmul_rn(x0m, x0m), __fmul_rn(x1m, x1m));
        float dot = __builtin_fmaf(x1n, x1m, __fmul_rn(x0n, x0m));
        float inner = __fmul_rn(-2.f, dot);
        float t1 = __fsub_rn(negxxn, inner);
        pdv[q] = __fsub_rn(t1, xxm);
    }

    int bins[16];
    int shift = 24;
    for (int attempt = 0; attempt < 3; ++attempt) {
        hist[tid] = 0;
        __syncthreads();
        float scale = (float)(1u << shift);
        #pragma unroll
        for (int q = 0; q < 16; ++q) {
            float s = fmaxf(-pdv[q], 0.f);
            unsigned int ki = (unsigned int)fminf(s * scale, 4.294e9f);
            unsigned int bin = ki >> 16;
            if (bin > 255u) bin = 255u;
            bins[q] = (int)bin;
            if (bin < 255u) atomicAdd(&hist[bin], 1u);
        }
        __syncthreads();
        if (tid < 64) {
            uint4 hv = *(const uint4*)&hist[tid * 4];
            unsigned int p0 = hv.x, p1 = p0 + hv.y, p2 = p1 + hv.z, p3 = p2 + hv.w;
            unsigned int lanesum = p3, inc = p3;
            #pragma unroll
            for (int s2 = 1; s2 < 64; s2 <<= 1) {
                unsigned int o = __shfl_up(inc, s2, 64);
                if (tid >= s2) inc += o;
            }
            unsigned int excl = inc - lanesum;
            bool flag = (inc >= KK);
            unsigned long long bal = __ballot(flag);
            int firstlane = (bal == 0ULL) ? -1 : (__ffsll((long long)bal) - 1);
            if (tid == 0) scanres[0] = (bal != 0ULL) ? 1u : 0u;
            if (tid == firstlane) {
                unsigned int c0 = excl + p0, c1 = excl + p1, c2 = excl + p2;
                int t = (c0 >= KK) ? 0 : (c1 >= KK) ? 1 : (c2 >= KK) ? 2 : 3;
                unsigned int cumb = (t == 0) ? excl : (t == 1) ? c0 : (t == 2) ? c1 : c2;
                scanres[1] = (unsigned)(tid * 4 + t);
                scanres[2] = cumb;
            }
        }
        __syncthreads();
        if (scanres[0]) break;
        shift -= 6;
        __syncthreads();
    }

    int bstar = (int)scanres[1];
    unsigned int cumb = scanres[2];
    if (tid == 0) { cnt2[0] = 0; cnt2[1] = 0; }
    __syncthreads();

    #pragma unroll
    for (int q = 0; q < 16; ++q) {
        int bin = bins[q];
        int m = q * 256 + tid;
        if (bin < bstar) {
            unsigned int slot = atomicAdd(&cnt2[0], 1u);
            idx[(size_t)r * KK + slot] = m;
        } else if (bin == bstar) {
            unsigned int pos = atomicAdd(&cnt2[1], 1u);
            if (pos < 512u) {
                unsigned int ub = __float_as_uint(pdv[q]);
                unsigned int fk = (ub & 0x80000000u) ? ~ub : (ub | 0x80000000u);
                blist[pos] = ((unsigned long long)(~fk) << 32) | (unsigned int)m;
            }
        }
    }
    __syncthreads();

    int need = KK - (int)cumb;
    int L = (int)min(cnt2[1], 512u);
    if (tid < 64) {
        unsigned long long e[8];
        #pragma unroll
        for (int i = 0; i < 8; ++i) {
            int p = tid + 64 * i;
            e[i] = (p < L) ? blist[p] : ~0ULL;
        }
        unsigned long long lmin = e[0];
        #pragma unroll
        for (int i = 1; i < 8; ++i) lmin = (e[i] < lmin) ? e[i] : lmin;
        for (int p = 0; p < need; ++p) {
            unsigned long long gm = lmin;
            #pragma unroll
            for (int s2 = 32; s2 > 0; s2 >>= 1) {
                unsigned long long o = __shfl_xor(gm, s2, 64);
                if (o < gm) gm = o;
            }
            if (lmin == gm) {
                #pragma unroll
                for (int i = 0; i < 8; ++i) if (e[i] == gm) e[i] = ~0ULL;
                lmin = e[0];
                #pragma unroll
                for (int i = 1; i < 8; ++i) lmin = (e[i] < lmin) ? e[i] : lmin;
                idx[(size_t)r * KK + cumb + p] = (int)(gm & 0xFFFFFFFFu);
            }
        }
    }
}

// ---------------------------------------------------------------------------
// Split-bf16 MFMA GEMM, 64x64 tile (verified R7-R10), f32 outputs.
__global__ __launch_bounds__(256) void mfma_gemm64(const unsigned short* __restrict__ Xh,
                                                   const unsigned short* __restrict__ Xl,
                                                   int ldx, int K,
                                                   const unsigned short* __restrict__ Bh,
                                                   const unsigned short* __restrict__ Bl,
                                                   int O,
                                                   float* __restrict__ outU,
                                                   float* __restrict__ outV) {
    __shared__ unsigned short Ah[256 * 8], Al[256 * 8], Bhs[256 * 8], Bls[256 * 8];
    int row0 = blockIdx.x * 64, col0 = blockIdx.y * 64;
    int tid = threadIdx.x;
    int wid = tid >> 6, lane = tid & 63;
    int wm = wid & 1, wn = wid >> 1;
    int l15 = lane & 15, l4 = lane >> 4;
    int m = tid & 63, kb = tid >> 6;

    f4 acc[2][2];
    #pragma unroll
    for (int i = 0; i < 2; ++i)
        #pragma unroll
        for (int j = 0; j < 2; ++j) { acc[i][j][0]=0.f; acc[i][j][1]=0.f; acc[i][j][2]=0.f; acc[i][j][3]=0.f; }

    for (int k0 = 0; k0 < K; k0 += 32) {
        size_t ga = (size_t)(row0 + m) * ldx + k0 + kb * 8;
        size_t gb = (size_t)(col0 + m) * K + k0 + kb * 8;
        gload16(Xh + ga, &Ah[(size_t)(wid * 64) * 8]);
        gload16(Xl + ga, &Al[(size_t)(wid * 64) * 8]);
        gload16(Bh + gb, &Bhs[(size_t)(wid * 64) * 8]);
        gload16(Bl + gb, &Bls[(size_t)(wid * 64) * 8]);
        __syncthreads();

        sv8 bhf[2], blf[2];
        #pragma unroll
        for (int fn = 0; fn < 2; ++fn) {
            int nn2 = wn * 32 + fn * 16 + l15;
            bhf[fn] = *(const sv8*)&Bhs[(size_t)(l4 * 64 + nn2) * 8];
            blf[fn] = *(const sv8*)&Bls[(size_t)(l4 * 64 + nn2) * 8];
        }
        #pragma unroll
        for (int fm = 0; fm < 2; ++fm) {
            int mm = wm * 32 + fm * 16 + l15;
            sv8 ah = *(const sv8*)&Ah[(size_t)(l4 * 64 + mm) * 8];
            sv8 al = *(const sv8*)&Al[(size_t)(l4 * 64 + mm) * 8];
            #pragma unroll
            for (int fn = 0; fn < 2; ++fn) {
                acc[fm][fn] = __builtin_amdgcn_mfma_f32_16x16x32_bf16(ah, bhf[fn], acc[fm][fn], 0, 0, 0);
                acc[fm][fn] = __builtin_amdgcn_mfma_f32_16x16x32_bf16(ah, blf[fn], acc[fm][fn], 0, 0, 0);
                acc[fm][fn] = __builtin_amdgcn_mfma_f32_16x16x32_bf16(al, bhf[fn], acc[fm][fn], 0, 0, 0);
            }
        }
        __syncthreads();
    }

    #pragma unroll
    for (int fm = 0; fm < 2; ++fm) {
        int rbase = row0 + wm * 32 + fm * 16 + l4 * 4;
        #pragma unroll
        for (int fn = 0; fn < 2; ++fn) {
            int jg = col0 + wn * 32 + fn * 16 + l15;
            #pragma unroll
            for (int e = 0; e < 4; ++e) {
                float vv = acc[fm][fn][e];
                int p = rbase + e;
                if (jg < O) outU[(size_t)p * O + jg] = vv;
                else        outV[(size_t)p * O + (jg - O)] = vv;
            }
        }
    }
}

// ---------------------------------------------------------------------------
// Single-plane bf16 MFMA GEMM, 128x128 tile (final conv) + fused BN stats via
// low-fan-in atomics (64 adds/address — measured fine in R11).
__global__ __launch_bounds__(256) void mfma_gemm128s(const unsigned short* __restrict__ Xh,
                                                     int ldx, int K,
                                                     const unsigned short* __restrict__ Bh,
                                                     int O,
                                                     float* __restrict__ outU,
                                                     float* __restrict__ facc) {
    __shared__ unsigned short Ah[512 * 8], Bhs[512 * 8];
    __shared__ float sred1[2][128], sred2[2][128];
    int row0 = blockIdx.x * 128, col0 = blockIdx.y * 128;
    int tid = threadIdx.x;
    int wid = tid >> 6, lane = tid & 63;
    int wm = wid & 1, wn = wid >> 1;
    int l15 = lane & 15, l4 = lane >> 4;

    f4 acc[4][4];
    #pragma unroll
    for (int i = 0; i < 4; ++i)
        #pragma unroll
        for (int j = 0; j < 4; ++j) { acc[i][j][0]=0.f; acc[i][j][1]=0.f; acc[i][j][2]=0.f; acc[i][j][3]=0.f; }

    for (int k0 = 0; k0 < K; k0 += 32) {
        #pragma unroll
        for (int j = 0; j < 2; ++j) {
            int c = tid + 256 * j;
            int m = c & 127, kb = c >> 7;
            size_t ga = (size_t)(row0 + m) * ldx + k0 + kb * 8;
            size_t gb = (size_t)(col0 + m) * K + k0 + kb * 8;
            gload16(Xh + ga, &Ah[(size_t)(wid * 64 + 256 * j) * 8]);
            gload16(Bh + gb, &Bhs[(size_t)(wid * 64 + 256 * j) * 8]);
        }
        __syncthreads();

        sv8 bhf[4];
        #pragma unroll
        for (int fn = 0; fn < 4; ++fn) {
            int nn2 = wn * 64 + fn * 16 + l15;
            bhf[fn] = *(const sv8*)&Bhs[(size_t)(l4 * 128 + nn2) * 8];
        }
        #pragma unroll
        for (int fm = 0; fm < 4; ++fm) {
            int mm = wm * 64 + fm * 16 + l15;
            sv8 ah = *(const sv8*)&Ah[(size_t)(l4 * 128 + mm) * 8];
            #pragma unroll
            for (int fn = 0; fn < 4; ++fn)
                acc[fm][fn] = __builtin_amdgcn_mfma_f32_16x16x32_bf16(ah, bhf[fn], acc[fm][fn], 0, 0, 0);
        }
        __syncthreads();
    }

    #pragma unroll
    for (int fm = 0; fm < 4; ++fm) {
        int rbase = row0 + wm * 64 + fm * 16 + l4 * 4;
        #pragma unroll
        for (int fn = 0; fn < 4; ++fn) {
            int jg = col0 + wn * 64 + fn * 16 + l15;
            #pragma unroll
            for (int e = 0; e < 4; ++e)
                outU[(size_t)(rbase + e) * O + jg] = acc[fm][fn][e];
        }
    }

    #pragma unroll
    for (int fn = 0; fn < 4; ++fn) {
        float a1 = 0.f, a2 = 0.f;
        #pragma unroll
        for (int fm = 0; fm < 4; ++fm)
            #pragma unroll
            for (int e = 0; e < 4; ++e) { float t = acc[fm][fn][e]; a1 += t; a2 = fmaf(t, t, a2); }
        a1 += __shfl_xor(a1, 16, 64); a2 += __shfl_xor(a2, 16, 64);
        a1 += __shfl_xor(a1, 32, 64); a2 += __shfl_xor(a2, 32, 64);
        if (lane < 16) {
            int cb = wn * 64 + fn * 16 + lane;
            sred1[wm][cb] = a1;
            sred2[wm][cb] = a2;
        }
    }
    __syncthreads();
    if (tid < 128) {
        float s1 = sred1[0][tid] + sred1[1][tid];
        float s2 = sred2[0][tid] + sred2[1][tid];
        atomicAdd(&facc[(size_t)(col0 + tid) * 2],     s1);
        atomicAdd(&facc[(size_t)(col0 + tid) * 2 + 1], s2);
    }
}

// ---------------------------------------------------------------------------
// edge_stats v2 (verified R6-R10): f32 float2 channel pairs, full prefetch,
// LDS-reduced per-block sums -> partial[blk][2*O].
__global__ __launch_bounds__(256) void edge_stats(const float* __restrict__ u,
                                                  const float* __restrict__ v,
                                                  const int* __restrict__ idx,
                                                  int O, int PPL,
                                                  float* __restrict__ mx, float* __restrict__ mn,
                                                  float* __restrict__ partial) {
    __shared__ float red[4 * 256];
    int tid = threadIdx.x;
    int CH2 = O >> 1;
    int PS = 256 / CH2;
    int co = tid % CH2;
    int ps = tid / CH2;
    float s1a = 0.f, s1b = 0.f, s2a = 0.f, s2b = 0.f;
    for (int pi = 0; pi < PPL; ++pi) {
        int r = (blockIdx.x * PS + ps) * PPL + pi;
        int b = r >> 12;
        const float* ub = u + (size_t)b * NN * O + 2 * co;
        float2 vv = *(const float2*)&v[(size_t)r * O + 2 * co];
        const int* ip = idx + (size_t)r * KK;
        int mreg[KK];
        #pragma unroll
        for (int k = 0; k < KK; ++k) mreg[k] = ip[k];
        float2 uv[KK];
        #pragma unroll
        for (int k = 0; k < KK; ++k) uv[k] = *(const float2*)&ub[(size_t)mreg[k] * O];
        float bxa = -INFINITY, bxb = -INFINITY, bna = INFINITY, bnb = INFINITY;
        #pragma unroll
        for (int k = 0; k < KK; ++k) {
            float y0 = uv[k].x + vv.x, y1 = uv[k].y + vv.y;
            s1a += y0; s2a = fmaf(y0, y0, s2a);
            s1b += y1; s2b = fmaf(y1, y1, s2b);
            bxa = fmaxf(bxa, y0); bna = fminf(bna, y0);
            bxb = fmaxf(bxb, y1); bnb = fminf(bnb, y1);
        }
        *(float2*)&mx[(size_t)r * O + 2 * co] = make_float2(bxa, bxb);
        *(float2*)&mn[(size_t)r * O + 2 * co] = make_float2(bna, bnb);
    }
    red[0 * 256 + tid] = s1a;
    red[1 * 256 + tid] = s1b;
    red[2 * 256 + tid] = s2a;
    red[3 * 256 + tid] = s2b;
    __syncthreads();
    for (int s = PS >> 1; s > 0; s >>= 1) {
        if (ps < s) {
            int oth = tid + s * CH2;
            red[0 * 256 + tid] += red[0 * 256 + oth];
            red[1 * 256 + tid] += red[1 * 256 + oth];
            red[2 * 256 + tid] += red[2 * 256 + oth];
            red[3 * 256 + tid] += red[3 * 256 + oth];
        }
        __syncthreads();
    }
    if (ps == 0) {
        size_t base = (size_t)blockIdx.x * 2 * O;
        partial[base + 2 * co]         = red[0 * 256 + tid];
        partial[base + 2 * co + 1]     = red[1 * 256 + tid];
        partial[base + O + 2 * co]     = red[2 * 256 + tid];
        partial[base + O + 2 * co + 1] = red[3 * 256 + tid];
    }
}

// reduce partial[blk][2*O] -> per-channel scale/shift.  grid = O blocks.
__global__ __launch_bounds__(256) void stats_reduce(const float* __restrict__ partial, int nblk,
                                                    int O, float cnt,
                                                    const float* __restrict__ g,
                                                    const float* __restrict__ bsh,
                                                    float* __restrict__ st) {
    __shared__ float r1[4], r2[4];
    int o = blockIdx.x, tid = threadIdx.x;
    float s1 = 0.f, s2 = 0.f;
    for (int bk = tid; bk < nblk; bk += 256) {
        size_t base = (size_t)bk * 2 * O;
        s1 += partial[base + o];
        s2 += partial[base + O + o];
    }
    #pragma unroll
    for (int s = 32; s > 0; s >>= 1) {
        s1 += __shfl_down(s1, s, 64);
        s2 += __shfl_down(s2, s, 64);
    }
    if ((tid & 63) == 0) { r1[tid >> 6] = s1; r2[tid >> 6] = s2; }
    __syncthreads();
    if (tid == 0) {
        s1 = r1[0] + r1[1] + r1[2] + r1[3];
        s2 = r2[0] + r2[1] + r2[2] + r2[3];
        float mu = s1 / cnt;
        float var = s2 / cnt - mu * mu;
        float x = var + EPSB;
        float rr = rsqrtf(x);
        rr = rr * (1.5f - 0.5f * x * rr * rr);
        float sc = g[o] * rr;
        st[o] = sc;
        st[O + o] = bsh[o] - mu * sc;
    }
}

// select max/min by scale sign, affine + LeakyReLU; 2 channels/thread.
__global__ void apply_edge(const float* __restrict__ mx, const float* __restrict__ mn,
                           const float* __restrict__ st, int O, int choff,
                           unsigned short* __restrict__ xh, unsigned short* __restrict__ xl,
                           int writelo) {
    int e2 = blockIdx.x * 256 + threadIdx.x;
    int half = O >> 1;
    if (e2 >= PP * half) return;
    int r = e2 / half, o = (e2 - r * half) * 2;
    float2 sc = *(const float2*)&st[o];
    float2 tt = *(const float2*)&st[O + o];
    float2 vx = *(const float2*)&mx[(size_t)r * O + o];
    float2 vn = *(const float2*)&mn[(size_t)r * O + o];
    float b0 = (sc.x >= 0.f) ? vx.x : vn.x;
    float b1 = (sc.y >= 0.f) ? vx.y : vn.y;
    float y0 = fmaf(sc.x, b0, tt.x); y0 = (y0 >= 0.f) ? y0 : LEAK * y0;
    float y1 = fmaf(sc.y, b1, tt.y); y1 = (y1 >= 0.f) ? y1 : LEAK * y1;
    unsigned short h0 = f2bf(y0), h1 = f2bf(y1);
    size_t d = (size_t)r * 512 + choff + o;
    ((unsigned int*)xh)[d >> 1] = (unsigned int)h0 | ((unsigned int)h1 << 16);
    if (writelo) {
        unsigned short l0 = f2bf(y0 - bf2f(h0)), l1 = f2bf(y1 - bf2f(h1));
        ((unsigned int*)xl)[d >> 1] = (unsigned int)l0 | ((unsigned int)l1 << 16);
    }
}

// ---------------------------------------------------------------------------
// affine+lrelu + transpose (B,N,512) -> (B,512,N); st inline from facc.
__global__ __launch_bounds__(256) void final_apply(const float* __restrict__ y5,
                                                   const float* __restrict__ facc,
                                                   const float* __restrict__ g,
                                                   const float* __restrict__ bsh,
                                                   float cnt,
                                                   float* __restrict__ out) {
    __shared__ float tile[32][33];
    int n0 = blockIdx.x * 32, o0 = blockIdx.y * 32, b = blockIdx.z;
    int tx = threadIdx.x, ty = threadIdx.y;
    for (int i = 0; i < 4; ++i) {
        int nl = ty + i * 8;
        tile[nl][tx] = y5[((size_t)(b * NN + n0 + nl)) * 512 + o0 + tx];
    }
    __syncthreads();
    for (int i = 0; i < 4; ++i) {
        int ol = ty + i * 8;
        int o = o0 + ol;
        float2 a = *(const float2*)&facc[(size_t)o * 2];   // s1, s2
        float mu = a.x / cnt;
        float var = a.y / cnt - mu * mu;
        float x = var + EPSB;
        float rr = rsqrtf(x);
        rr = rr * (1.5f - 0.5f * x * rr * rr);
        float sc = g[o] * rr;
        float tt = bsh[o] - mu * sc;
        float yv = fmaf(sc, tile[tx][ol], tt);
        yv = (yv >= 0.f) ? yv : LEAK * yv;
        out[((size_t)b * 512 + o) * NN + n0 + tx] = yv;
    }
}

// ---------------------------------------------------------------------------
extern "C" void kernel_launch(void* const* d_in, const int* in_sizes, int n_in,
                              void* d_out, int out_size, void* d_ws, size_t ws_size,
                              hipStream_t stream) {
    const float* pts = (const float*)d_in[0];
    const float* w[5]; const float* g[5]; const float* bsh[5];
    for (int i = 0; i < 5; ++i) {
        w[i]   = (const float*)d_in[1 + 3 * i];
        g[i]   = (const float*)d_in[2 + 3 * i];
        bsh[i] = (const float*)d_in[3 + 3 * i];
    }
    float* out = (float*)d_out;

    // workspace layout (R10-verified sizes + facc)
    unsigned short* xh = (unsigned short*)d_ws;              // PP*512 bf16 hi
    unsigned short* xl = xh + (size_t)PP * 512;              // PP*512 bf16 lo
    float* u    = (float*)(xl + (size_t)PP * 512);           // PP*256 f32
    float* v    = u    + (size_t)PP * 256;                   // PP*256 f32
    float* mxb  = v    + (size_t)PP * 256;                   // PP*256 f32
    float* mnb  = mxb  + (size_t)PP * 256;                   // PP*256 f32
    float* y5   = mxb;                                       // overlay (PP*512, mx/mn dead by then)
    int*   idxb = (int*)(mnb + (size_t)PP * 256);            // PP*20
    float* part = (float*)(idxb + (size_t)PP * KK);          // 1M floats (4MB)
    float* st   = part + (size_t)1048576;                    // 1024
    float* facc = st + 1024;                                 // 1024 (zeroed by knn)
    unsigned short* wh_all = (unsigned short*)(facc + 1024); // 352256 persistent
    unsigned short* wl_all = wh_all + 352256;                // 352256

    knn_kernel<<<PP, 256, 0, stream>>>(pts, idxb, w[0], u, v,
                                       w[1], w[2], w[3], w[4], wh_all, wl_all, facc);

    const int Cs[4]     = {2, 64, 64, 128};
    const int Os[4]     = {64, 64, 128, 256};
    const int choffs[4] = {0, 64, 128, 256};
    const int inoffs[4] = {0, 0, 64, 128};
    const int woffs[4]  = {0, 0, 8192, 24576};
    float cntE = (float)((size_t)PP * KK);

    for (int li = 0; li < 4; ++li) {
        int C = Cs[li], O = Os[li];
        if (li > 0) {
            dim3 gg(PP / 64, (2 * O) / 64);
            mfma_gemm64<<<gg, 256, 0, stream>>>(xh + inoffs[li], xl + inoffs[li], 512, C,
                                                wh_all + woffs[li], wl_all + woffs[li], O, u, v);
        }
        int PS  = 512 / O;
        int PPL = (O == 256) ? 2 : 1;
        int nblk = PP / (PS * PPL);
        edge_stats<<<nblk, 256, 0, stream>>>(u, v, idxb, O, PPL, mxb, mnb, part);
        stats_reduce<<<O, 256, 0, stream>>>(part, nblk, O, cntE, g[li], bsh[li], st);
        apply_edge<<<(PP * O / 2 + 255) / 256, 256, 0, stream>>>(
            mxb, mnb, st, O, choffs[li], xh, xl, (li == 3) ? 0 : 1);
    }

    // final conv1d 512->512 (single-plane bf16 MFMA, low-fan-in atomic stats)
    dim3 gf(PP / 128, 512 / 128);
    mfma_gemm128s<<<gf, 256, 0, stream>>>(xh, 512, 512, wh_all + 90112, 512, y5, facc);
    final_apply<<<dim3(NN / 32, 512 / 32, BB), dim3(32, 8), 0, stream>>>(
        y5, facc, g[4], bsh[4], (float)PP, out);
}